// Round 2
// baseline (54595.612 us; speedup 1.0000x reference)
//
#include <hip/hip_runtime.h>
#include <math.h>

#define SQ   4096
#define EDIM 512
#define CEDIM 128
#define CHH  128
#define WH   512
#define NT   50
#define NWGW 16

__device__ __forceinline__ float sigf(float x) { return 1.0f / (1.0f + expf(-x)); }

// ---------------------------------------------------------------------------
// K1: gather word/char embedding rows; compute char-LSTM input GEMM
//     cgx[d][t][r] = sum_k ce[t][k]*cWih[d][r][k] + cb[d][r]
// grid 256 x 256 threads, each block handles 16 sequence rows
// ---------------------------------------------------------------------------
__global__ __launch_bounds__(256) void k1_gather_cgx(
    const int* __restrict__ sent, const int* __restrict__ csent,
    const float* __restrict__ wemb, const float* __restrict__ cemb,
    const float* __restrict__ cWih_f, const float* __restrict__ cb_f,
    const float* __restrict__ cWih_b, const float* __restrict__ cb_b,
    float* __restrict__ we_g, float* __restrict__ cgx)
{
    const int tid = threadIdx.x;
    const int t0 = blockIdx.x * 16;
    __shared__ __align__(16) float ceL[16][128];
    __shared__ int sids[16], cids[16];
    if (tid < 16) sids[tid] = sent[t0 + tid];
    else if (tid < 32) cids[tid - 16] = csent[t0 + tid - 16];
    __syncthreads();
    // char rows -> LDS: 16 rows * 32 float4 = 512 float4
    {
        int f4 = tid;
        for (int q = 0; q < 2; ++q, f4 += 256) {
            int r = f4 >> 5, k4 = f4 & 31;
            float4 v = *(const float4*)&cemb[(size_t)cids[r] * CEDIM + k4 * 4];
            *(float4*)&ceL[r][k4 * 4] = v;
        }
    }
    // word rows -> global we_g: 16 rows * 128 float4 = 2048 float4
    {
        int f4 = tid;
        for (int q = 0; q < 8; ++q, f4 += 256) {
            int r = f4 >> 7, k4 = f4 & 127;
            float4 v = *(const float4*)&wemb[(size_t)sids[r] * EDIM + k4 * 4];
            *(float4*)&we_g[(size_t)(t0 + r) * EDIM + k4 * 4] = v;
        }
    }
    __syncthreads();
    // cgx: 2 dirs * 512 rows, each thread does 4 (dir,row) pairs x 16 timesteps
    for (int q = 0; q < 4; ++q) {
        int j = q * 256 + tid;
        int d = j >> 9, r = j & 511;
        const float* Wih = d ? cWih_b : cWih_f;
        const float* cb = d ? cb_b : cb_f;
        float b = cb[r];
        float acc[16];
#pragma unroll
        for (int tt = 0; tt < 16; ++tt) acc[tt] = b;
        for (int k4 = 0; k4 < 32; ++k4) {
            float4 wv = *(const float4*)&Wih[r * CEDIM + k4 * 4];
#pragma unroll
            for (int tt = 0; tt < 16; ++tt) {
                acc[tt] += wv.x * ceL[tt][k4 * 4 + 0] + wv.y * ceL[tt][k4 * 4 + 1]
                         + wv.z * ceL[tt][k4 * 4 + 2] + wv.w * ceL[tt][k4 * 4 + 3];
            }
        }
#pragma unroll
        for (int tt = 0; tt < 16; ++tt)
            cgx[((size_t)d * SQ + (t0 + tt)) * 512 + r] = acc[tt];
    }
}

// ---------------------------------------------------------------------------
// K2: role-split kernel.
//   blocks 0,1  : char BiLSTM direction (weights register-resident, 1 CU each)
//   blocks 2+   : GEMM wgx[d][t][r] = we_g[t][0:512] . wWih[d][r][0:512] + wb
// ---------------------------------------------------------------------------
__global__ __launch_bounds__(512, 2) void k2_charlstm_gemm(
    const float* __restrict__ cWhh_f, const float* __restrict__ cWhh_b,
    const float* __restrict__ cgx, float* __restrict__ cho,
    const float* __restrict__ we_g,
    const float* __restrict__ wWih_f, const float* __restrict__ wb_f,
    const float* __restrict__ wWih_b, const float* __restrict__ wb_b,
    float* __restrict__ wgx)
{
    const int tid = threadIdx.x;
    __shared__ __align__(16) float At[32][68];
    __shared__ __align__(16) float Bt[32][128];
    __shared__ __align__(16) float hb[128];
    __shared__ __align__(16) float gb[512];

    if (blockIdx.x < 2) {
        // ---------------- char LSTM ----------------
        const int dir = blockIdx.x;
        const float* Whh = dir ? cWhh_b : cWhh_f;
        const int row = tid;               // = gate*128 + unit
        float w[128];
#pragma unroll
        for (int i = 0; i < 128; i += 4) {
            float4 v = *(const float4*)&Whh[(size_t)row * CHH + i];
            w[i] = v.x; w[i + 1] = v.y; w[i + 2] = v.z; w[i + 3] = v.w;
        }
        const float* gx = cgx + (size_t)dir * SQ * 512;
        float cst = 0.0f;
        if (tid < 32) *(float4*)&hb[tid * 4] = make_float4(0, 0, 0, 0);
        __syncthreads();
        for (int t = 0; t < SQ; ++t) {
            const int x = dir ? (SQ - 1 - t) : t;
            float a0 = 0.f, a1 = 0.f, a2 = 0.f, a3 = 0.f;
#pragma unroll
            for (int i = 0; i < 128; i += 4) {
                a0 += w[i] * hb[i];
                a1 += w[i + 1] * hb[i + 1];
                a2 += w[i + 2] * hb[i + 2];
                a3 += w[i + 3] * hb[i + 3];
            }
            gb[row] = (a0 + a1) + (a2 + a3) + gx[(size_t)x * 512 + row];
            __syncthreads();
            if (tid < 128) {
                float iv = gb[tid], fv = gb[128 + tid], gv = gb[256 + tid], ov = gb[384 + tid];
                cst = sigf(fv) * cst + sigf(iv) * tanhf(gv);
                float h = sigf(ov) * tanhf(cst);
                hb[tid] = h;
                cho[(size_t)x * 256 + dir * CHH + tid] = h;
            }
            __syncthreads();
        }
        return;
    }
    // ---------------- GEMM (word-emb part of word gx) ----------------
    const int tile = blockIdx.x - 2;
    const int dir = tile >> 10;
    const int rem = tile & 1023;
    const int mb = rem >> 4;   // 64-row block of t
    const int nb = rem & 15;   // 128-col block of r
    const float* Wih = dir ? wWih_b : wWih_f;
    const float* wb = dir ? wb_b : wb_f;
    float* C = wgx + (size_t)dir * SQ * 2048;
    const int tm = tid >> 5, tn = tid & 31;
    float acc[4][4];
#pragma unroll
    for (int i = 0; i < 4; ++i)
#pragma unroll
        for (int jj = 0; jj < 4; ++jj) acc[i][jj] = 0.f;
    for (int kb = 0; kb < 16; ++kb) {
        {
            int rowm = tid >> 3, k4 = tid & 7;
            float4 v = *(const float4*)&we_g[(size_t)(mb * 64 + rowm) * EDIM + kb * 32 + k4 * 4];
            At[k4 * 4 + 0][rowm] = v.x; At[k4 * 4 + 1][rowm] = v.y;
            At[k4 * 4 + 2][rowm] = v.z; At[k4 * 4 + 3][rowm] = v.w;
        }
#pragma unroll
        for (int q = 0; q < 2; ++q) {
            int f4 = q * 512 + tid;
            int rr = f4 >> 3, k4 = f4 & 7;
            float4 v = *(const float4*)&Wih[(size_t)(nb * 128 + rr) * 768 + kb * 32 + k4 * 4];
            Bt[k4 * 4 + 0][rr] = v.x; Bt[k4 * 4 + 1][rr] = v.y;
            Bt[k4 * 4 + 2][rr] = v.z; Bt[k4 * 4 + 3][rr] = v.w;
        }
        __syncthreads();
#pragma unroll
        for (int kk = 0; kk < 32; ++kk) {
            float4 a4 = *(const float4*)&At[kk][tm * 4];
            float4 b4 = *(const float4*)&Bt[kk][tn * 4];
            acc[0][0] += a4.x * b4.x; acc[0][1] += a4.x * b4.y; acc[0][2] += a4.x * b4.z; acc[0][3] += a4.x * b4.w;
            acc[1][0] += a4.y * b4.x; acc[1][1] += a4.y * b4.y; acc[1][2] += a4.y * b4.z; acc[1][3] += a4.y * b4.w;
            acc[2][0] += a4.z * b4.x; acc[2][1] += a4.z * b4.y; acc[2][2] += a4.z * b4.z; acc[2][3] += a4.z * b4.w;
            acc[3][0] += a4.w * b4.x; acc[3][1] += a4.w * b4.y; acc[3][2] += a4.w * b4.z; acc[3][3] += a4.w * b4.w;
        }
        __syncthreads();
    }
    float4 wbv = *(const float4*)&wb[nb * 128 + tn * 4];
#pragma unroll
    for (int i = 0; i < 4; ++i) {
        float4 o;
        o.x = acc[i][0] + wbv.x; o.y = acc[i][1] + wbv.y;
        o.z = acc[i][2] + wbv.z; o.w = acc[i][3] + wbv.w;
        *(float4*)&C[(size_t)(mb * 64 + tm * 4 + i) * 2048 + nb * 128 + tn * 4] = o;
    }
}

// ---------------------------------------------------------------------------
// K3: wgx += char_out . wWih[:,512:768]^T   (accumulate char contribution)
// ---------------------------------------------------------------------------
__global__ __launch_bounds__(512, 2) void k3_gemm_char(
    const float* __restrict__ cho,
    const float* __restrict__ wWih_f, const float* __restrict__ wWih_b,
    float* __restrict__ wgx)
{
    const int tid = threadIdx.x;
    const int tile = blockIdx.x;
    const int dir = tile >> 10;
    const int rem = tile & 1023;
    const int mb = rem >> 4, nb = rem & 15;
    const float* Wih = dir ? wWih_b : wWih_f;
    float* C = wgx + (size_t)dir * SQ * 2048;
    __shared__ __align__(16) float At[32][68];
    __shared__ __align__(16) float Bt[32][128];
    const int tm = tid >> 5, tn = tid & 31;
    float acc[4][4];
#pragma unroll
    for (int i = 0; i < 4; ++i)
#pragma unroll
        for (int jj = 0; jj < 4; ++jj) acc[i][jj] = 0.f;
    for (int kb = 0; kb < 8; ++kb) {
        {
            int rowm = tid >> 3, k4 = tid & 7;
            float4 v = *(const float4*)&cho[(size_t)(mb * 64 + rowm) * 256 + kb * 32 + k4 * 4];
            At[k4 * 4 + 0][rowm] = v.x; At[k4 * 4 + 1][rowm] = v.y;
            At[k4 * 4 + 2][rowm] = v.z; At[k4 * 4 + 3][rowm] = v.w;
        }
#pragma unroll
        for (int q = 0; q < 2; ++q) {
            int f4 = q * 512 + tid;
            int rr = f4 >> 3, k4 = f4 & 7;
            float4 v = *(const float4*)&Wih[(size_t)(nb * 128 + rr) * 768 + 512 + kb * 32 + k4 * 4];
            Bt[k4 * 4 + 0][rr] = v.x; Bt[k4 * 4 + 1][rr] = v.y;
            Bt[k4 * 4 + 2][rr] = v.z; Bt[k4 * 4 + 3][rr] = v.w;
        }
        __syncthreads();
#pragma unroll
        for (int kk = 0; kk < 32; ++kk) {
            float4 a4 = *(const float4*)&At[kk][tm * 4];
            float4 b4 = *(const float4*)&Bt[kk][tn * 4];
            acc[0][0] += a4.x * b4.x; acc[0][1] += a4.x * b4.y; acc[0][2] += a4.x * b4.z; acc[0][3] += a4.x * b4.w;
            acc[1][0] += a4.y * b4.x; acc[1][1] += a4.y * b4.y; acc[1][2] += a4.y * b4.z; acc[1][3] += a4.y * b4.w;
            acc[2][0] += a4.z * b4.x; acc[2][1] += a4.z * b4.y; acc[2][2] += a4.z * b4.z; acc[2][3] += a4.z * b4.w;
            acc[3][0] += a4.w * b4.x; acc[3][1] += a4.w * b4.y; acc[3][2] += a4.w * b4.z; acc[3][3] += a4.w * b4.w;
        }
        __syncthreads();
    }
#pragma unroll
    for (int i = 0; i < 4; ++i) {
        float* cp = &C[(size_t)(mb * 64 + tm * 4 + i) * 2048 + nb * 128 + tn * 4];
        float4 o = *(float4*)cp;
        o.x += acc[i][0]; o.y += acc[i][1]; o.z += acc[i][2]; o.w += acc[i][3];
        *(float4*)cp = o;
    }
}

// ---------------------------------------------------------------------------
// K4: word BiLSTM. 16 persistent WGs per direction, W_hh register-resident.
//     Per-step cross-WG sync via ctr[dir][t] release/acquire flags.
//     blockIdx%8==0 -> fwd, ==1 -> bwd (XCD-locality heuristic), grid=128.
// ---------------------------------------------------------------------------
__global__ __launch_bounds__(512, 2) void k4_word_lstm(
    const float* __restrict__ wWhh_f, const float* __restrict__ wWhh_b,
    const float* __restrict__ wgx, float* __restrict__ lstm, int* __restrict__ ctr)
{
    const int res = blockIdx.x & 7;
    if (res > 1) return;
    const int dir = res;
    const int wid = blockIdx.x >> 3;     // 0..15
    const int tid = threadIdx.x;
    const float* Whh = dir ? wWhh_b : wWhh_f;
    const int p = tid >> 2, c = tid & 3;
    const int j = p & 31, g = p >> 5;
    const int ub = wid * 32;
    const int row = g * WH + ub + j;
    float w[128];
#pragma unroll
    for (int i = 0; i < 128; i += 4) {
        float4 v = *(const float4*)&Whh[(size_t)row * WH + c * 128 + i];
        w[i] = v.x; w[i + 1] = v.y; w[i + 2] = v.z; w[i + 3] = v.w;
    }
    __shared__ __align__(16) float hb[512];
    __shared__ __align__(16) float gbuf[128];
    const float* gx = wgx + (size_t)dir * SQ * 2048;
    int* myctr = ctr + dir * SQ;
    float cst = 0.0f;
    for (int t = 0; t < SQ; ++t) {
        const int x = dir ? (SQ - 1 - t) : t;
        if (t == 0) {
            if (tid < 128) *(float4*)&hb[tid * 4] = make_float4(0, 0, 0, 0);
            __syncthreads();
        } else {
            if (tid == 0) {
                while (__hip_atomic_load(&myctr[t - 1], __ATOMIC_RELAXED, __HIP_MEMORY_SCOPE_AGENT) < NWGW)
                    __builtin_amdgcn_s_sleep(1);
            }
            __syncthreads();
            // every thread performs an acquire so each wave's L1 view is fresh
            (void)__hip_atomic_load(&myctr[t - 1], __ATOMIC_ACQUIRE, __HIP_MEMORY_SCOPE_AGENT);
            const int xp = dir ? (x + 1) : (x - 1);
            if (tid < 128) {
                float4 v = *(const float4*)&lstm[(size_t)xp * 1024 + dir * WH + tid * 4];
                *(float4*)&hb[tid * 4] = v;
            }
            __syncthreads();
        }
        float a0 = 0.f, a1 = 0.f, a2 = 0.f, a3 = 0.f;
        const int hbase = c * 128;
#pragma unroll
        for (int i = 0; i < 128; i += 4) {
            a0 += w[i] * hb[hbase + i];
            a1 += w[i + 1] * hb[hbase + i + 1];
            a2 += w[i + 2] * hb[hbase + i + 2];
            a3 += w[i + 3] * hb[hbase + i + 3];
        }
        float acc = (a0 + a1) + (a2 + a3);
        acc += __shfl_xor(acc, 1);
        acc += __shfl_xor(acc, 2);
        if (c == 0) gbuf[p] = acc;
        __syncthreads();
        if (tid < 32) {
            const int rb = ub + tid;
            const size_t gbase = (size_t)x * 2048;
            float iv = gbuf[tid]      + gx[gbase + rb];
            float fv = gbuf[32 + tid] + gx[gbase + 512 + rb];
            float gv = gbuf[64 + tid] + gx[gbase + 1024 + rb];
            float ov = gbuf[96 + tid] + gx[gbase + 1536 + rb];
            cst = sigf(fv) * cst + sigf(iv) * tanhf(gv);
            float h = sigf(ov) * tanhf(cst);
            lstm[(size_t)x * 1024 + dir * WH + rb] = h;
        }
        if (tid == 0)
            __hip_atomic_fetch_add(&myctr[t], 1, __ATOMIC_RELEASE, __HIP_MEMORY_SCOPE_AGENT);
    }
}

// ---------------------------------------------------------------------------
// K5: emissions = lstm_out @ W_tag^T + b_tag
// ---------------------------------------------------------------------------
__global__ __launch_bounds__(64) void k5_emis(
    const float* __restrict__ lstm, const float* __restrict__ Wtag,
    const float* __restrict__ btag, float* __restrict__ emis)
{
    const int t = blockIdx.x, tid = threadIdx.x;
    __shared__ __align__(16) float rowL[1024];
#pragma unroll
    for (int q = 0; q < 4; ++q) {
        int f4 = q * 64 + tid;
        *(float4*)&rowL[f4 * 4] = *(const float4*)&lstm[(size_t)t * 1024 + f4 * 4];
    }
    __syncthreads();
    if (tid < NT) {
        float a0 = 0.f, a1 = 0.f, a2 = 0.f, a3 = 0.f;
        const float* wr = Wtag + (size_t)tid * 1024;
        for (int k4 = 0; k4 < 256; ++k4) {
            float4 wv = *(const float4*)&wr[k4 * 4];
            a0 += wv.x * rowL[k4 * 4 + 0];
            a1 += wv.y * rowL[k4 * 4 + 1];
            a2 += wv.z * rowL[k4 * 4 + 2];
            a3 += wv.w * rowL[k4 * 4 + 3];
        }
        emis[(size_t)t * NT + tid] = btag[tid] + (a0 + a1) + (a2 + a3);
    }
}

// ---------------------------------------------------------------------------
// K6a: Viterbi forward (sequential), trans in registers, 4 p-groups.
//      Strict > with ascending p matches jnp.argmax first-max semantics.
// ---------------------------------------------------------------------------
__global__ __launch_bounds__(256) void k6a_viterbi(
    const float* __restrict__ emis, const float* __restrict__ start_t,
    const float* __restrict__ end_t, const float* __restrict__ trans,
    unsigned char* __restrict__ bpb, int* __restrict__ last)
{
    const int tid = threadIdx.x;
    const int g = tid >> 6, c = tid & 63;
    __shared__ float sc[64];
    __shared__ float pbest[4][64];
    __shared__ int pbp[4][64];
    const int p0 = g * 13;
    float tr[13];
#pragma unroll
    for (int i = 0; i < 13; ++i) {
        int p = p0 + i;
        tr[i] = (c < NT && p < NT) ? trans[p * NT + c] : -1e30f;
    }
    if (tid < 64) sc[tid] = (tid < NT) ? (start_t[tid] + emis[tid]) : -1e30f;
    __syncthreads();
    for (int t = 1; t < SQ; ++t) {
        float best = -1e30f; int bp = 0;
#pragma unroll
        for (int i = 0; i < 13; ++i) {
            float v = sc[p0 + i] + tr[i];
            if (v > best) { best = v; bp = p0 + i; }
        }
        pbest[g][c] = best; pbp[g][c] = bp;
        __syncthreads();
        if (tid < NT) {
            float b = pbest[0][tid]; int bb = pbp[0][tid];
#pragma unroll
            for (int gg = 1; gg < 4; ++gg) {
                float v = pbest[gg][tid];
                if (v > b) { b = v; bb = pbp[gg][tid]; }
            }
            bpb[(size_t)t * NT + tid] = (unsigned char)bb;
            sc[tid] = b + emis[(size_t)t * NT + tid];
        }
        __syncthreads();
    }
    if (tid == 0) {
        float b = -1e30f; int bi = 0;
        for (int cc = 0; cc < NT; ++cc) {
            float v = sc[cc] + end_t[cc];
            if (v > b) { b = v; bi = cc; }
        }
        *last = bi;
    }
}

// K6b: per-chunk end-tag -> end-of-previous-chunk-tag maps (parallel walks)
__global__ __launch_bounds__(64) void k6b_maps(
    const unsigned char* __restrict__ bpb, int* __restrict__ map_)
{
    const int k = blockIdx.x;
    const int e = threadIdx.x;
    if (k == 0 || e >= NT) return;
    int tag = e;
    for (int i = 63; i >= 0; --i) {
        int t = k * 64 + i;
        tag = bpb[(size_t)t * NT + tag];
    }
    map_[k * NT + e] = tag;
}

// K6c: stitch chunk boundary tags, then emit path in parallel
__global__ __launch_bounds__(64) void k6c_backtrack(
    const unsigned char* __restrict__ bpb, const int* __restrict__ map_,
    const int* __restrict__ last, int* __restrict__ path)
{
    __shared__ int B[64];
    if (threadIdx.x == 0) {
        int tag = *last;
        B[63] = tag;
        for (int k = 63; k >= 1; --k) {
            tag = map_[k * NT + tag];
            B[k - 1] = tag;
        }
    }
    __syncthreads();
    const int k = threadIdx.x;
    int tag = B[k];
    for (int i = 63; i >= 0; --i) {
        int t = k * 64 + i;
        path[t] = tag;
        if (t >= 1) tag = bpb[(size_t)t * NT + tag];
    }
}

// ---------------------------------------------------------------------------
extern "C" void kernel_launch(void* const* d_in, const int* in_sizes, int n_in,
                              void* d_out, int out_size, void* d_ws, size_t ws_size,
                              hipStream_t stream)
{
    const int* sent = (const int*)d_in[0];
    const int* csent = (const int*)d_in[1];
    const float* wemb = (const float*)d_in[2];
    const float* cemb = (const float*)d_in[3];
    const float* cWih_f = (const float*)d_in[4];
    const float* cWhh_f = (const float*)d_in[5];
    const float* cb_f = (const float*)d_in[6];
    const float* cWih_b = (const float*)d_in[7];
    const float* cWhh_b = (const float*)d_in[8];
    const float* cb_b = (const float*)d_in[9];
    const float* wWih_f = (const float*)d_in[10];
    const float* wWhh_f = (const float*)d_in[11];
    const float* wb_f = (const float*)d_in[12];
    const float* wWih_b = (const float*)d_in[13];
    const float* wWhh_b = (const float*)d_in[14];
    const float* wb_b = (const float*)d_in[15];
    const float* Wtag = (const float*)d_in[16];
    const float* btag = (const float*)d_in[17];
    const float* start_t = (const float*)d_in[18];
    const float* end_t = (const float*)d_in[19];
    const float* trans = (const float*)d_in[20];
    int* path = (int*)d_out;

    float* ws = (float*)d_ws;
    float* we_g = ws;                                   // SQ*EDIM
    float* cgx  = we_g + (size_t)SQ * EDIM;             // 2*SQ*512
    float* cho  = cgx + (size_t)2 * SQ * 512;           // SQ*256
    float* wgx  = cho + (size_t)SQ * 256;               // 2*SQ*2048
    float* lstm = wgx + (size_t)2 * SQ * 2048;          // SQ*1024
    float* emis = lstm + (size_t)SQ * 1024;             // SQ*NT
    int* ctr    = (int*)(emis + (size_t)SQ * NT);       // 2*SQ
    int* map_   = ctr + 2 * SQ;                         // 64*NT
    int* lastp  = map_ + 64 * NT;                       // 1 (+pad)
    unsigned char* bpb = (unsigned char*)(lastp + 4);   // SQ*NT bytes

    hipMemsetAsync(ctr, 0, 2 * SQ * sizeof(int), stream);

    k1_gather_cgx<<<SQ / 16, 256, 0, stream>>>(sent, csent, wemb, cemb,
                                               cWih_f, cb_f, cWih_b, cb_b, we_g, cgx);
    k2_charlstm_gemm<<<2 + 2048, 512, 0, stream>>>(cWhh_f, cWhh_b, cgx, cho, we_g,
                                                   wWih_f, wb_f, wWih_b, wb_b, wgx);
    k3_gemm_char<<<2048, 512, 0, stream>>>(cho, wWih_f, wWih_b, wgx);
    k4_word_lstm<<<128, 512, 0, stream>>>(wWhh_f, wWhh_b, wgx, lstm, ctr);
    k5_emis<<<SQ, 64, 0, stream>>>(lstm, Wtag, btag, emis);
    k6a_viterbi<<<1, 256, 0, stream>>>(emis, start_t, end_t, trans, bpb, lastp);
    k6b_maps<<<64, 64, 0, stream>>>(bpb, map_);
    k6c_backtrack<<<1, 64, 0, stream>>>(bpb, map_, lastp, path);
}

// Round 3
// 17419.072 us; speedup vs baseline: 3.1342x; 3.1342x over previous
//
#include <hip/hip_runtime.h>
#include <math.h>

#define SQ   4096
#define EDIM 512
#define CEDIM 128
#define CHH  128
#define WH   512
#define NT   50
#define NWGW 16

__device__ __forceinline__ float sigf(float x) { return 1.0f / (1.0f + expf(-x)); }

// Named-register weight hold: 32 float4 = 128 floats, immune to rematerialization.
#define WLOAD(n) const float4 w##n = wp[n];
#define WLOAD_ALL \
  WLOAD(0) WLOAD(1) WLOAD(2) WLOAD(3) WLOAD(4) WLOAD(5) WLOAD(6) WLOAD(7) \
  WLOAD(8) WLOAD(9) WLOAD(10) WLOAD(11) WLOAD(12) WLOAD(13) WLOAD(14) WLOAD(15) \
  WLOAD(16) WLOAD(17) WLOAD(18) WLOAD(19) WLOAD(20) WLOAD(21) WLOAD(22) WLOAD(23) \
  WLOAD(24) WLOAD(25) WLOAD(26) WLOAD(27) WLOAD(28) WLOAD(29) WLOAD(30) WLOAD(31)
#define WDOT(n) \
  a0 += w##n.x * hs[4*n+0]; a1 += w##n.y * hs[4*n+1]; \
  a2 += w##n.z * hs[4*n+2]; a3 += w##n.w * hs[4*n+3];
#define WDOT_ALL \
  WDOT(0) WDOT(1) WDOT(2) WDOT(3) WDOT(4) WDOT(5) WDOT(6) WDOT(7) \
  WDOT(8) WDOT(9) WDOT(10) WDOT(11) WDOT(12) WDOT(13) WDOT(14) WDOT(15) \
  WDOT(16) WDOT(17) WDOT(18) WDOT(19) WDOT(20) WDOT(21) WDOT(22) WDOT(23) \
  WDOT(24) WDOT(25) WDOT(26) WDOT(27) WDOT(28) WDOT(29) WDOT(30) WDOT(31)

// ---------------------------------------------------------------------------
// K1: gather word/char embedding rows; compute char-LSTM input GEMM
// ---------------------------------------------------------------------------
__global__ __launch_bounds__(256) void k1_gather_cgx(
    const int* __restrict__ sent, const int* __restrict__ csent,
    const float* __restrict__ wemb, const float* __restrict__ cemb,
    const float* __restrict__ cWih_f, const float* __restrict__ cb_f,
    const float* __restrict__ cWih_b, const float* __restrict__ cb_b,
    float* __restrict__ we_g, float* __restrict__ cgx)
{
    const int tid = threadIdx.x;
    const int t0 = blockIdx.x * 16;
    __shared__ __align__(16) float ceL[16][128];
    __shared__ int sids[16], cids[16];
    if (tid < 16) sids[tid] = sent[t0 + tid];
    else if (tid < 32) cids[tid - 16] = csent[t0 + tid - 16];
    __syncthreads();
    {
        int f4 = tid;
        for (int q = 0; q < 2; ++q, f4 += 256) {
            int r = f4 >> 5, k4 = f4 & 31;
            float4 v = *(const float4*)&cemb[(size_t)cids[r] * CEDIM + k4 * 4];
            *(float4*)&ceL[r][k4 * 4] = v;
        }
    }
    {
        int f4 = tid;
        for (int q = 0; q < 8; ++q, f4 += 256) {
            int r = f4 >> 7, k4 = f4 & 127;
            float4 v = *(const float4*)&wemb[(size_t)sids[r] * EDIM + k4 * 4];
            *(float4*)&we_g[(size_t)(t0 + r) * EDIM + k4 * 4] = v;
        }
    }
    __syncthreads();
    for (int q = 0; q < 4; ++q) {
        int j = q * 256 + tid;
        int d = j >> 9, r = j & 511;
        const float* Wih = d ? cWih_b : cWih_f;
        const float* cb = d ? cb_b : cb_f;
        float b = cb[r];
        float acc[16];
#pragma unroll
        for (int tt = 0; tt < 16; ++tt) acc[tt] = b;
        for (int k4 = 0; k4 < 32; ++k4) {
            float4 wv = *(const float4*)&Wih[r * CEDIM + k4 * 4];
#pragma unroll
            for (int tt = 0; tt < 16; ++tt) {
                acc[tt] += wv.x * ceL[tt][k4 * 4 + 0] + wv.y * ceL[tt][k4 * 4 + 1]
                         + wv.z * ceL[tt][k4 * 4 + 2] + wv.w * ceL[tt][k4 * 4 + 3];
            }
        }
#pragma unroll
        for (int tt = 0; tt < 16; ++tt)
            cgx[((size_t)d * SQ + (t0 + tt)) * 512 + r] = acc[tt];
    }
}

// ---------------------------------------------------------------------------
// K2: blocks 0,1 = char BiLSTM (weights in named registers); blocks 2+ = GEMM
// ---------------------------------------------------------------------------
__global__ __launch_bounds__(512, 2) void k2_charlstm_gemm(
    const float* __restrict__ cWhh_f, const float* __restrict__ cWhh_b,
    const float* __restrict__ cgx, float* __restrict__ cho,
    const float* __restrict__ we_g,
    const float* __restrict__ wWih_f, const float* __restrict__ wb_f,
    const float* __restrict__ wWih_b, const float* __restrict__ wb_b,
    float* __restrict__ wgx)
{
    const int tid = threadIdx.x;
    __shared__ __align__(16) float At[32][68];
    __shared__ __align__(16) float Bt[32][128];
    __shared__ __align__(16) float hb[128];
    __shared__ __align__(16) float gb[512];

    if (blockIdx.x < 2) {
        const int dir = blockIdx.x;
        const float* Whh = dir ? cWhh_b : cWhh_f;
        const int row = tid;               // gate*128 + unit
        const float4* wp = (const float4*)&Whh[(size_t)row * CHH];
        WLOAD_ALL
        const float* gx = cgx + (size_t)dir * SQ * 512;
        float cst = 0.0f;
        if (tid < 32) *(float4*)&hb[tid * 4] = make_float4(0, 0, 0, 0);
        __syncthreads();
        for (int t = 0; t < SQ; ++t) {
            const int x = dir ? (SQ - 1 - t) : t;
            float gxv = gx[(size_t)x * 512 + row];
            const float* hs = hb;
            float a0 = 0.f, a1 = 0.f, a2 = 0.f, a3 = 0.f;
            WDOT_ALL
            gb[row] = (a0 + a1) + (a2 + a3) + gxv;
            __syncthreads();
            if (tid < 128) {
                float iv = gb[tid], fv = gb[128 + tid], gv = gb[256 + tid], ov = gb[384 + tid];
                cst = sigf(fv) * cst + sigf(iv) * tanhf(gv);
                float h = sigf(ov) * tanhf(cst);
                hb[tid] = h;
                cho[(size_t)x * 256 + dir * CHH + tid] = h;
            }
            __syncthreads();
        }
        return;
    }
    // ---------------- GEMM (word-emb part of word gx) ----------------
    const int tile = blockIdx.x - 2;
    const int dir = tile >> 10;
    const int rem = tile & 1023;
    const int mb = rem >> 4;
    const int nb = rem & 15;
    const float* Wih = dir ? wWih_b : wWih_f;
    const float* wb = dir ? wb_b : wb_f;
    float* C = wgx + (size_t)dir * SQ * 2048;
    const int tm = tid >> 5, tn = tid & 31;
    float acc[4][4];
#pragma unroll
    for (int i = 0; i < 4; ++i)
#pragma unroll
        for (int jj = 0; jj < 4; ++jj) acc[i][jj] = 0.f;
    for (int kb = 0; kb < 16; ++kb) {
        {
            int rowm = tid >> 3, k4 = tid & 7;
            float4 v = *(const float4*)&we_g[(size_t)(mb * 64 + rowm) * EDIM + kb * 32 + k4 * 4];
            At[k4 * 4 + 0][rowm] = v.x; At[k4 * 4 + 1][rowm] = v.y;
            At[k4 * 4 + 2][rowm] = v.z; At[k4 * 4 + 3][rowm] = v.w;
        }
#pragma unroll
        for (int q = 0; q < 2; ++q) {
            int f4 = q * 512 + tid;
            int rr = f4 >> 3, k4 = f4 & 7;
            float4 v = *(const float4*)&Wih[(size_t)(nb * 128 + rr) * 768 + kb * 32 + k4 * 4];
            Bt[k4 * 4 + 0][rr] = v.x; Bt[k4 * 4 + 1][rr] = v.y;
            Bt[k4 * 4 + 2][rr] = v.z; Bt[k4 * 4 + 3][rr] = v.w;
        }
        __syncthreads();
#pragma unroll
        for (int kk = 0; kk < 32; ++kk) {
            float4 a4 = *(const float4*)&At[kk][tm * 4];
            float4 b4 = *(const float4*)&Bt[kk][tn * 4];
            acc[0][0] += a4.x * b4.x; acc[0][1] += a4.x * b4.y; acc[0][2] += a4.x * b4.z; acc[0][3] += a4.x * b4.w;
            acc[1][0] += a4.y * b4.x; acc[1][1] += a4.y * b4.y; acc[1][2] += a4.y * b4.z; acc[1][3] += a4.y * b4.w;
            acc[2][0] += a4.z * b4.x; acc[2][1] += a4.z * b4.y; acc[2][2] += a4.z * b4.z; acc[2][3] += a4.z * b4.w;
            acc[3][0] += a4.w * b4.x; acc[3][1] += a4.w * b4.y; acc[3][2] += a4.w * b4.z; acc[3][3] += a4.w * b4.w;
        }
        __syncthreads();
    }
    float4 wbv = *(const float4*)&wb[nb * 128 + tn * 4];
#pragma unroll
    for (int i = 0; i < 4; ++i) {
        float4 o;
        o.x = acc[i][0] + wbv.x; o.y = acc[i][1] + wbv.y;
        o.z = acc[i][2] + wbv.z; o.w = acc[i][3] + wbv.w;
        *(float4*)&C[(size_t)(mb * 64 + tm * 4 + i) * 2048 + nb * 128 + tn * 4] = o;
    }
}

// ---------------------------------------------------------------------------
// K3: wgx += char_out . wWih[:,512:768]^T
// ---------------------------------------------------------------------------
__global__ __launch_bounds__(512, 2) void k3_gemm_char(
    const float* __restrict__ cho,
    const float* __restrict__ wWih_f, const float* __restrict__ wWih_b,
    float* __restrict__ wgx)
{
    const int tid = threadIdx.x;
    const int tile = blockIdx.x;
    const int dir = tile >> 10;
    const int rem = tile & 1023;
    const int mb = rem >> 4, nb = rem & 15;
    const float* Wih = dir ? wWih_b : wWih_f;
    float* C = wgx + (size_t)dir * SQ * 2048;
    __shared__ __align__(16) float At[32][68];
    __shared__ __align__(16) float Bt[32][128];
    const int tm = tid >> 5, tn = tid & 31;
    float acc[4][4];
#pragma unroll
    for (int i = 0; i < 4; ++i)
#pragma unroll
        for (int jj = 0; jj < 4; ++jj) acc[i][jj] = 0.f;
    for (int kb = 0; kb < 8; ++kb) {
        {
            int rowm = tid >> 3, k4 = tid & 7;
            float4 v = *(const float4*)&cho[(size_t)(mb * 64 + rowm) * 256 + kb * 32 + k4 * 4];
            At[k4 * 4 + 0][rowm] = v.x; At[k4 * 4 + 1][rowm] = v.y;
            At[k4 * 4 + 2][rowm] = v.z; At[k4 * 4 + 3][rowm] = v.w;
        }
#pragma unroll
        for (int q = 0; q < 2; ++q) {
            int f4 = q * 512 + tid;
            int rr = f4 >> 3, k4 = f4 & 7;
            float4 v = *(const float4*)&Wih[(size_t)(nb * 128 + rr) * 768 + 512 + kb * 32 + k4 * 4];
            Bt[k4 * 4 + 0][rr] = v.x; Bt[k4 * 4 + 1][rr] = v.y;
            Bt[k4 * 4 + 2][rr] = v.z; Bt[k4 * 4 + 3][rr] = v.w;
        }
        __syncthreads();
#pragma unroll
        for (int kk = 0; kk < 32; ++kk) {
            float4 a4 = *(const float4*)&At[kk][tm * 4];
            float4 b4 = *(const float4*)&Bt[kk][tn * 4];
            acc[0][0] += a4.x * b4.x; acc[0][1] += a4.x * b4.y; acc[0][2] += a4.x * b4.z; acc[0][3] += a4.x * b4.w;
            acc[1][0] += a4.y * b4.x; acc[1][1] += a4.y * b4.y; acc[1][2] += a4.y * b4.z; acc[1][3] += a4.y * b4.w;
            acc[2][0] += a4.z * b4.x; acc[2][1] += a4.z * b4.y; acc[2][2] += a4.z * b4.z; acc[2][3] += a4.z * b4.w;
            acc[3][0] += a4.w * b4.x; acc[3][1] += a4.w * b4.y; acc[3][2] += a4.w * b4.z; acc[3][3] += a4.w * b4.w;
        }
        __syncthreads();
    }
#pragma unroll
    for (int i = 0; i < 4; ++i) {
        float* cp = &C[(size_t)(mb * 64 + tm * 4 + i) * 2048 + nb * 128 + tn * 4];
        float4 o = *(float4*)cp;
        o.x += acc[i][0]; o.y += acc[i][1]; o.z += acc[i][2]; o.w += acc[i][3];
        *(float4*)cp = o;
    }
}

// ---------------------------------------------------------------------------
// K4: word BiLSTM, 16 persistent WGs/direction.
//     Weights in named registers; h exchange via cache-bypass (RELAXED,AGENT)
//     atomics; flags relaxed; explicit vmcnt drain orders store->flag.
// ---------------------------------------------------------------------------
__global__ __launch_bounds__(512, 2) void k4_word_lstm(
    const float* __restrict__ wWhh_f, const float* __restrict__ wWhh_b,
    const float* __restrict__ wgx, float* __restrict__ lstm, int* __restrict__ ctr)
{
    const int res = blockIdx.x & 7;
    if (res > 1) return;
    const int dir = res;
    const int wid = blockIdx.x >> 3;     // 0..15
    const int tid = threadIdx.x;
    const float* Whh = dir ? wWhh_b : wWhh_f;
    const int p = tid >> 2, c = tid & 3;
    const int j = p & 31, g = p >> 5;
    const int ub = wid * 32;
    const int row = g * WH + ub + j;
    const float4* wp = (const float4*)&Whh[(size_t)row * WH + c * 128];
    WLOAD_ALL
    __shared__ __align__(16) float hb[544];   // 4 chunks of 128, stride 132 (bank spread)
    __shared__ __align__(16) float gbuf[128];
    const float* gx = wgx + (size_t)dir * SQ * 2048;
    int* myctr = ctr + dir * SQ;
    float cst = 0.0f;
    for (int t = 0; t < SQ; ++t) {
        const int x = dir ? (SQ - 1 - t) : t;
        // prefetch gate inputs (independent of h) before the flag wait
        float gxi = 0.f, gxf = 0.f, gxg = 0.f, gxo = 0.f;
        if (tid < 32) {
            const size_t gbase = (size_t)x * 2048 + ub + tid;
            gxi = gx[gbase]; gxf = gx[gbase + 512];
            gxg = gx[gbase + 1024]; gxo = gx[gbase + 1536];
        }
        if (t == 0) {
            if (tid < 128) {
                int pb = tid * 4 + (tid >> 5) * 4;
                hb[pb] = 0.f; hb[pb + 1] = 0.f; hb[pb + 2] = 0.f; hb[pb + 3] = 0.f;
            }
        } else {
            if (tid == 0) {
                while (__hip_atomic_load(&myctr[t - 1], __ATOMIC_RELAXED, __HIP_MEMORY_SCOPE_AGENT) < NWGW)
                    __builtin_amdgcn_s_sleep(2);
            }
            __syncthreads();
            const int xp = dir ? (x + 1) : (x - 1);
            if (tid < 128) {
                const float* hp = &lstm[(size_t)xp * 1024 + dir * WH + tid * 4];
                float h0 = __hip_atomic_load(hp + 0, __ATOMIC_RELAXED, __HIP_MEMORY_SCOPE_AGENT);
                float h1 = __hip_atomic_load(hp + 1, __ATOMIC_RELAXED, __HIP_MEMORY_SCOPE_AGENT);
                float h2 = __hip_atomic_load(hp + 2, __ATOMIC_RELAXED, __HIP_MEMORY_SCOPE_AGENT);
                float h3 = __hip_atomic_load(hp + 3, __ATOMIC_RELAXED, __HIP_MEMORY_SCOPE_AGENT);
                int pb = tid * 4 + (tid >> 5) * 4;
                hb[pb] = h0; hb[pb + 1] = h1; hb[pb + 2] = h2; hb[pb + 3] = h3;
            }
        }
        __syncthreads();
        const float* hs = &hb[c * 132];
        float a0 = 0.f, a1 = 0.f, a2 = 0.f, a3 = 0.f;
        WDOT_ALL
        float acc = (a0 + a1) + (a2 + a3);
        acc += __shfl_xor(acc, 1);
        acc += __shfl_xor(acc, 2);
        if (c == 0) gbuf[p] = acc;
        __syncthreads();
        if (tid < 32) {
            const int rb = ub + tid;
            float iv = gbuf[tid]      + gxi;
            float fv = gbuf[32 + tid] + gxf;
            float gv = gbuf[64 + tid] + gxg;
            float ov = gbuf[96 + tid] + gxo;
            cst = sigf(fv) * cst + sigf(iv) * tanhf(gv);
            float h = sigf(ov) * tanhf(cst);
            __hip_atomic_store(&lstm[(size_t)x * 1024 + dir * WH + rb], h,
                               __ATOMIC_RELAXED, __HIP_MEMORY_SCOPE_AGENT);
            asm volatile("s_waitcnt vmcnt(0)" ::: "memory");
            if (tid == 0)
                __hip_atomic_fetch_add(&myctr[t], 1, __ATOMIC_RELAXED, __HIP_MEMORY_SCOPE_AGENT);
        }
    }
}

// ---------------------------------------------------------------------------
// K5: emissions = lstm_out @ W_tag^T + b_tag
// ---------------------------------------------------------------------------
__global__ __launch_bounds__(64) void k5_emis(
    const float* __restrict__ lstm, const float* __restrict__ Wtag,
    const float* __restrict__ btag, float* __restrict__ emis)
{
    const int t = blockIdx.x, tid = threadIdx.x;
    __shared__ __align__(16) float rowL[1024];
#pragma unroll
    for (int q = 0; q < 4; ++q) {
        int f4 = q * 64 + tid;
        *(float4*)&rowL[f4 * 4] = *(const float4*)&lstm[(size_t)t * 1024 + f4 * 4];
    }
    __syncthreads();
    if (tid < NT) {
        float a0 = 0.f, a1 = 0.f, a2 = 0.f, a3 = 0.f;
        const float* wr = Wtag + (size_t)tid * 1024;
        for (int k4 = 0; k4 < 256; ++k4) {
            float4 wv = *(const float4*)&wr[k4 * 4];
            a0 += wv.x * rowL[k4 * 4 + 0];
            a1 += wv.y * rowL[k4 * 4 + 1];
            a2 += wv.z * rowL[k4 * 4 + 2];
            a3 += wv.w * rowL[k4 * 4 + 3];
        }
        emis[(size_t)t * NT + tid] = btag[tid] + (a0 + a1) + (a2 + a3);
    }
}

// ---------------------------------------------------------------------------
// K6a: Viterbi forward (sequential)
// ---------------------------------------------------------------------------
__global__ __launch_bounds__(256) void k6a_viterbi(
    const float* __restrict__ emis, const float* __restrict__ start_t,
    const float* __restrict__ end_t, const float* __restrict__ trans,
    unsigned char* __restrict__ bpb, int* __restrict__ last)
{
    const int tid = threadIdx.x;
    const int g = tid >> 6, c = tid & 63;
    __shared__ float sc[64];
    __shared__ float pbest[4][64];
    __shared__ int pbp[4][64];
    const int p0 = g * 13;
    float tr[13];
#pragma unroll
    for (int i = 0; i < 13; ++i) {
        int p = p0 + i;
        tr[i] = (c < NT && p < NT) ? trans[p * NT + c] : -1e30f;
    }
    if (tid < 64) sc[tid] = (tid < NT) ? (start_t[tid] + emis[tid]) : -1e30f;
    __syncthreads();
    for (int t = 1; t < SQ; ++t) {
        float best = -1e30f; int bp = 0;
#pragma unroll
        for (int i = 0; i < 13; ++i) {
            float v = sc[p0 + i] + tr[i];
            if (v > best) { best = v; bp = p0 + i; }
        }
        pbest[g][c] = best; pbp[g][c] = bp;
        __syncthreads();
        if (tid < NT) {
            float b = pbest[0][tid]; int bb = pbp[0][tid];
#pragma unroll
            for (int gg = 1; gg < 4; ++gg) {
                float v = pbest[gg][tid];
                if (v > b) { b = v; bb = pbp[gg][tid]; }
            }
            bpb[(size_t)t * NT + tid] = (unsigned char)bb;
            sc[tid] = b + emis[(size_t)t * NT + tid];
        }
        __syncthreads();
    }
    if (tid == 0) {
        float b = -1e30f; int bi = 0;
        for (int cc = 0; cc < NT; ++cc) {
            float v = sc[cc] + end_t[cc];
            if (v > b) { b = v; bi = cc; }
        }
        *last = bi;
    }
}

// K6b: per-chunk end-tag -> end-of-previous-chunk-tag maps
__global__ __launch_bounds__(64) void k6b_maps(
    const unsigned char* __restrict__ bpb, int* __restrict__ map_)
{
    const int k = blockIdx.x;
    const int e = threadIdx.x;
    if (k == 0 || e >= NT) return;
    int tag = e;
    for (int i = 63; i >= 0; --i) {
        int t = k * 64 + i;
        tag = bpb[(size_t)t * NT + tag];
    }
    map_[k * NT + e] = tag;
}

// K6c: stitch chunk boundary tags, emit path
__global__ __launch_bounds__(64) void k6c_backtrack(
    const unsigned char* __restrict__ bpb, const int* __restrict__ map_,
    const int* __restrict__ last, int* __restrict__ path)
{
    __shared__ int B[64];
    if (threadIdx.x == 0) {
        int tag = *last;
        B[63] = tag;
        for (int k = 63; k >= 1; --k) {
            tag = map_[k * NT + tag];
            B[k - 1] = tag;
        }
    }
    __syncthreads();
    const int k = threadIdx.x;
    int tag = B[k];
    for (int i = 63; i >= 0; --i) {
        int t = k * 64 + i;
        path[t] = tag;
        if (t >= 1) tag = bpb[(size_t)t * NT + tag];
    }
}

// ---------------------------------------------------------------------------
extern "C" void kernel_launch(void* const* d_in, const int* in_sizes, int n_in,
                              void* d_out, int out_size, void* d_ws, size_t ws_size,
                              hipStream_t stream)
{
    const int* sent = (const int*)d_in[0];
    const int* csent = (const int*)d_in[1];
    const float* wemb = (const float*)d_in[2];
    const float* cemb = (const float*)d_in[3];
    const float* cWih_f = (const float*)d_in[4];
    const float* cWhh_f = (const float*)d_in[5];
    const float* cb_f = (const float*)d_in[6];
    const float* cWih_b = (const float*)d_in[7];
    const float* cWhh_b = (const float*)d_in[8];
    const float* cb_b = (const float*)d_in[9];
    const float* wWih_f = (const float*)d_in[10];
    const float* wWhh_f = (const float*)d_in[11];
    const float* wb_f = (const float*)d_in[12];
    const float* wWih_b = (const float*)d_in[13];
    const float* wWhh_b = (const float*)d_in[14];
    const float* wb_b = (const float*)d_in[15];
    const float* Wtag = (const float*)d_in[16];
    const float* btag = (const float*)d_in[17];
    const float* start_t = (const float*)d_in[18];
    const float* end_t = (const float*)d_in[19];
    const float* trans = (const float*)d_in[20];
    int* path = (int*)d_out;

    float* ws = (float*)d_ws;
    float* we_g = ws;                                   // SQ*EDIM
    float* cgx  = we_g + (size_t)SQ * EDIM;             // 2*SQ*512
    float* cho  = cgx + (size_t)2 * SQ * 512;           // SQ*256
    float* wgx  = cho + (size_t)SQ * 256;               // 2*SQ*2048
    float* lstm = wgx + (size_t)2 * SQ * 2048;          // SQ*1024
    float* emis = lstm + (size_t)SQ * 1024;             // SQ*NT
    int* ctr    = (int*)(emis + (size_t)SQ * NT);       // 2*SQ
    int* map_   = ctr + 2 * SQ;                         // 64*NT
    int* lastp  = map_ + 64 * NT;                       // 1 (+pad)
    unsigned char* bpb = (unsigned char*)(lastp + 4);   // SQ*NT bytes

    hipMemsetAsync(ctr, 0, 2 * SQ * sizeof(int), stream);

    k1_gather_cgx<<<SQ / 16, 256, 0, stream>>>(sent, csent, wemb, cemb,
                                               cWih_f, cb_f, cWih_b, cb_b, we_g, cgx);
    k2_charlstm_gemm<<<2 + 2048, 512, 0, stream>>>(cWhh_f, cWhh_b, cgx, cho, we_g,
                                                   wWih_f, wb_f, wWih_b, wb_b, wgx);
    k3_gemm_char<<<2048, 512, 0, stream>>>(cho, wWih_f, wWih_b, wgx);
    k4_word_lstm<<<128, 512, 0, stream>>>(wWhh_f, wWhh_b, wgx, lstm, ctr);
    k5_emis<<<SQ, 64, 0, stream>>>(lstm, Wtag, btag, emis);
    k6a_viterbi<<<1, 256, 0, stream>>>(emis, start_t, end_t, trans, bpb, lastp);
    k6b_maps<<<64, 64, 0, stream>>>(bpb, map_);
    k6c_backtrack<<<1, 64, 0, stream>>>(bpb, map_, lastp, path);
}